// Round 10
// baseline (112.692 us; speedup 1.0000x reference)
//
#include <hip/hip_runtime.h>
#include <math.h>

// Problem constants
constexpr int NB  = 8;     // batch
constexpr int C   = 256;   // channels
constexpr int T   = 1024;  // pixels (32*32)
constexpr int NH  = 8;     // heads
constexpr int HD  = 32;    // head dim
constexpr int C3  = 768;   // 3*C

// Q pre-scale: (1/sqrt(32)) * log2(e)  -> softmax body is a bare v_exp_f32
constexpr float QSCALE = 0.25503489422229562f;

typedef __attribute__((ext_vector_type(8))) short bf16x8;
typedef __attribute__((ext_vector_type(4))) float f32x4;

__device__ inline short f2bf(float f) {            // round-to-nearest-even
    unsigned u = __float_as_uint(f);
    u += 0x7FFF + ((u >> 16) & 1);
    return (short)(u >> 16);
}
__device__ inline short f2bf_trunc(float f) {      // 1-op truncation (P only)
    return (short)(__float_as_uint(f) >> 16);
}

// ---------------------------------------------------------------------------
// Kernel 1: KQV projection, bf16 MFMA, 128x64 (m x n) tile, BK=32.
// Inputs read fp32, transpose-converted in the LDS staging scatter.
// K/Q written head-major [nb][h][t][d]; V written TRANSPOSED per 64-row tile:
// Vtb[nb][h][tile=t/64][d][t%64]. Q pre-scaled by QSCALE. (unchanged from R8)
// ---------------------------------------------------------------------------
__global__ __launch_bounds__(256) void kqv_mfma(const float* __restrict__ image,
                                                const float* __restrict__ wkqv,
                                                const float* __restrict__ bkqv,
                                                short* __restrict__ Kb,
                                                short* __restrict__ Qb,
                                                short* __restrict__ Vtb) {
    __shared__ __align__(16) short As[128][40];
    __shared__ __align__(16) short Bs[64][40];
    const int tid = threadIdx.x;
    const int n0 = blockIdx.x * 64;        // 0..704
    const int m0 = blockIdx.y * 128;
    const int nb = m0 >> 10, t0 = m0 & 1023;
    const int wv = tid >> 6, lane = tid & 63;
    const int m = lane & 15, quad = lane >> 4;
    const int am = tid & 63, ak8 = (tid >> 6) * 8;    // staging map (both A & B)

    const float* imgn = image + (size_t)nb * C * T;

    f32x4 acc[2][4];
    const f32x4 z = {0.f, 0.f, 0.f, 0.f};
    #pragma unroll
    for (int i = 0; i < 2; ++i)
        #pragma unroll
        for (int j = 0; j < 4; ++j) acc[i][j] = z;

    // prefetch first K-slab (fp32): A two 64-row halves, B one 64-col tile
    float fa[2][8], fb[8];
    #pragma unroll
    for (int i = 0; i < 8; ++i) {
        fa[0][i] = imgn[(size_t)(ak8 + i) * T + t0 + am];
        fa[1][i] = imgn[(size_t)(ak8 + i) * T + t0 + 64 + am];
        fb[i]    = wkqv[(size_t)(ak8 + i) * C3 + n0 + am];
    }

    for (int k0 = 0; k0 < C; k0 += 32) {
        __syncthreads();                   // prior frag reads done
        #pragma unroll
        for (int h2 = 0; h2 < 2; ++h2) {
            short4 lo = { f2bf(fa[h2][0]), f2bf(fa[h2][1]), f2bf(fa[h2][2]), f2bf(fa[h2][3]) };
            short4 hi = { f2bf(fa[h2][4]), f2bf(fa[h2][5]), f2bf(fa[h2][6]), f2bf(fa[h2][7]) };
            *(short4*)&As[64 * h2 + am][ak8]     = lo;
            *(short4*)&As[64 * h2 + am][ak8 + 4] = hi;
        }
        {
            short4 lo = { f2bf(fb[0]), f2bf(fb[1]), f2bf(fb[2]), f2bf(fb[3]) };
            short4 hi = { f2bf(fb[4]), f2bf(fb[5]), f2bf(fb[6]), f2bf(fb[7]) };
            *(short4*)&Bs[am][ak8]     = lo;
            *(short4*)&Bs[am][ak8 + 4] = hi;
        }
        if (k0 + 32 < C) {
            #pragma unroll
            for (int i = 0; i < 8; ++i) {
                fa[0][i] = imgn[(size_t)(k0 + 32 + ak8 + i) * T + t0 + am];
                fa[1][i] = imgn[(size_t)(k0 + 32 + ak8 + i) * T + t0 + 64 + am];
                fb[i]    = wkqv[(size_t)(k0 + 32 + ak8 + i) * C3 + n0 + am];
            }
        }
        __syncthreads();
        bf16x8 a[2], b[4];
        #pragma unroll
        for (int i = 0; i < 2; ++i) a[i] = *(const bf16x8*)&As[32 * wv + 16 * i + m][8 * quad];
        #pragma unroll
        for (int j = 0; j < 4; ++j) b[j] = *(const bf16x8*)&Bs[16 * j + m][8 * quad];
        #pragma unroll
        for (int i = 0; i < 2; ++i)
            #pragma unroll
            for (int j = 0; j < 4; ++j)
                acc[i][j] = __builtin_amdgcn_mfma_f32_16x16x32_bf16(a[i], b[j], acc[i][j], 0, 0, 0);
    }

    // epilogue: col jj -> (chunk,h,d); rows = 4 consecutive t per reg set
    #pragma unroll
    for (int j = 0; j < 4; ++j) {
        int jj = n0 + 16 * j + m;
        int chunk = jj >> 8, hh = (jj >> 5) & 7, d = jj & 31;
        float bias = bkqv[jj];
        if (chunk < 2) {
            short* dst = (chunk == 0) ? Kb : Qb;
            float mul = (chunk == 1) ? QSCALE : 1.0f;
            size_t base = (size_t)(nb * NH + hh) * T * HD + d;
            #pragma unroll
            for (int i = 0; i < 2; ++i) {
                int t = t0 + 32 * wv + 16 * i + 4 * quad;
                #pragma unroll
                for (int r = 0; r < 4; ++r)
                    dst[base + (size_t)(t + r) * HD] = f2bf((acc[i][j][r] + bias) * mul);
            }
        } else {
            // V: transposed tile layout [nb][h][tile][d][64]
            size_t base = (size_t)(nb * NH + hh) * (16 * 2048) + (size_t)d * 64;
            #pragma unroll
            for (int i = 0; i < 2; ++i) {
                #pragma unroll
                for (int r = 0; r < 4; ++r) {
                    int t = t0 + 32 * wv + 16 * i + 4 * quad + r;
                    Vtb[base + (size_t)(t >> 6) * 2048 + (t & 63)] = f2bf(acc[i][j][r] + bias);
                }
            }
        }
    }
}

// ---------------------------------------------------------------------------
// Kernel 2: causal flash attention — barrier-free, DETERMINISTICALLY BALANCED.
// 64-row q-tiles; block p handles the complementary pair {15-p', p'} IN-BLOCK
// (p' = blockIdx.x), so every block does exactly 17 identical 64x64-tile
// iterations — no scheduler-pairing assumption. 512 blocks = 2/CU.
// All MFMA fragments except P load directly from global as contiguous 16B
// (Q/K head-major, V pre-transposed per tile). Ps (64x72) is the only LDS;
// each wave touches only its own 16-row band -> zero __syncthreads.
// ---------------------------------------------------------------------------
__global__ __launch_bounds__(256) void attn_mfma(const short* __restrict__ Kb,
                                                 const short* __restrict__ Qb,
                                                 const short* __restrict__ Vtb,
                                                 short* __restrict__ attnb) {
    const int pr = blockIdx.x;     // 0..7 -> pair {15-pr, pr}
    const int h  = blockIdx.y;
    const int nb = blockIdx.z;
    const int tid  = threadIdx.x;
    const int wv   = tid >> 6;
    const int lane = tid & 63;
    const int m    = lane & 15;
    const int quad = lane >> 4;

    __shared__ __align__(16) short Ps[64][72];   // probs bf16, wave-private bands

    const size_t hb = (size_t)(nb * NH + h) * T * HD;
    const short* Kp = Kb + hb;
    const short* Qp = Qb + hb;
    const short* Vp = Vtb + (size_t)(nb * NH + h) * (16 * 2048);
    const f32x4 z = {0.f, 0.f, 0.f, 0.f};

    #pragma unroll 1
    for (int half = 0; half < 2; ++half) {
        const int qt  = half ? pr : 15 - pr;     // big tile first
        const int q0  = qt * 64;
        const int nst = qt + 1;

        // Q fragment for this tile: wave wv owns rows 16wv..16wv+15
        bf16x8 aq = *(const bf16x8*)&Qp[(size_t)(q0 + 16 * wv + m) * HD + 8 * quad];

        // preload K/V fragments for st = 0
        bf16x8 bk[4], vb[2][2];
        #pragma unroll
        for (int j = 0; j < 4; ++j)
            bk[j] = *(const bf16x8*)&Kp[(size_t)(16 * j + m) * HD + 8 * quad];
        #pragma unroll
        for (int kc = 0; kc < 2; ++kc)
            #pragma unroll
            for (int hf = 0; hf < 2; ++hf)
                vb[kc][hf] = *(const bf16x8*)&Vp[(size_t)(16 * hf + m) * 64 + 32 * kc + 8 * quad];

        f32x4 O[2] = {z, z};
        float lp[4] = {};

        for (int st = 0; st < nst; ++st) {
            // S = Q K^T : 1 row-group x 4 col-tiles = 4 MFMA
            f32x4 S[4];
            #pragma unroll
            for (int j = 0; j < 4; ++j)
                S[j] = __builtin_amdgcn_mfma_f32_16x16x32_bf16(aq, bk[j], z, 0, 0, 0);

            // prefetch next K tile
            if (st + 1 < nst) {
                #pragma unroll
                for (int j = 0; j < 4; ++j)
                    bk[j] = *(const bf16x8*)&Kp[(size_t)((st + 1) * 64 + 16 * j + m) * HD + 8 * quad];
            }

            // softmax: bare exp2 (Q pre-scaled); mask only the diagonal tile
            const bool msk = (st == qt);
            const int s0 = st * 64;
            const int qr_base = q0 + 16 * wv + 4 * quad;
            #pragma unroll
            for (int j = 0; j < 4; ++j) {
                const int sc = s0 + 16 * j + m;
                #pragma unroll
                for (int r = 0; r < 4; ++r) {
                    float e = __builtin_amdgcn_exp2f(S[j][r]);
                    if (msk && sc > qr_base + r) e = 0.f;
                    lp[r] += e;
                    Ps[16 * wv + 4 * quad + r][16 * j + m] = f2bf_trunc(e);
                }
            }

            // O += P V (Ps band is wave-private; lgkmcnt ordering suffices)
            #pragma unroll
            for (int kc = 0; kc < 2; ++kc) {
                bf16x8 ap = *(const bf16x8*)&Ps[16 * wv + m][32 * kc + 8 * quad];
                O[0] = __builtin_amdgcn_mfma_f32_16x16x32_bf16(ap, vb[kc][0], O[0], 0, 0, 0);
                O[1] = __builtin_amdgcn_mfma_f32_16x16x32_bf16(ap, vb[kc][1], O[1], 0, 0, 0);
            }

            // prefetch next V tile
            if (st + 1 < nst) {
                const short* Vn = Vp + (size_t)(st + 1) * 2048;
                #pragma unroll
                for (int kc = 0; kc < 2; ++kc)
                    #pragma unroll
                    for (int hf = 0; hf < 2; ++hf)
                        vb[kc][hf] = *(const bf16x8*)&Vn[(size_t)(16 * hf + m) * 64 + 32 * kc + 8 * quad];
            }
        }

        // epilogue: reduce l across 16 m-lanes once, normalize, store bf16
        #pragma unroll
        for (int r = 0; r < 4; ++r) {
            float l = lp[r];
            l += __shfl_xor(l, 1);
            l += __shfl_xor(l, 2);
            l += __shfl_xor(l, 4);
            l += __shfl_xor(l, 8);
            float inv = 1.f / l;
            int row = q0 + 16 * wv + 4 * quad + r;
            short* op = attnb + ((size_t)(nb * T + row)) * C + h * HD;
            op[m]      = f2bf(O[0][r] * inv);
            op[16 + m] = f2bf(O[1][r] * inv);
        }
    }
}

// ---------------------------------------------------------------------------
// Kernel 3: mix projection + residual. A-frags (attnb, k-contiguous) load
// DIRECTLY from global; w_mix tile (256x64) is transpose-staged into LDS once
// -> ONE barrier total, fully-unrolled barrier-free K-loop. (unchanged)
// ---------------------------------------------------------------------------
__global__ __launch_bounds__(256) void mix_mfma(const short* __restrict__ attnb,
                                                const float* __restrict__ wmix,
                                                const float* __restrict__ bmix,
                                                const float* __restrict__ image,
                                                float* __restrict__ out) {
    __shared__ __align__(16) short Bs[64][264];   // [n][k], stride 264 (16B-mult)
    const int tid = threadIdx.x;
    const int n0 = blockIdx.x * 64;        // 0..192
    const int m0 = blockIdx.y * 64;
    const int nb = m0 >> 10, t0 = m0 & 1023;
    const int wv = tid >> 6, lane = tid & 63;
    const int m = lane & 15, quad = lane >> 4;
    const int bn = tid & 63, bk8 = (tid >> 6) * 8;   // staging: n, k-base

    // stage entire B tile (transpose-convert): k = bk8 + 32g + i
    #pragma unroll
    for (int g = 0; g < 8; ++g) {
        int kk = bk8 + 32 * g;
        float fb[8];
        #pragma unroll
        for (int i = 0; i < 8; ++i)
            fb[i] = wmix[(size_t)(kk + i) * C + n0 + bn];
        short4 lo = { f2bf(fb[0]), f2bf(fb[1]), f2bf(fb[2]), f2bf(fb[3]) };
        short4 hi = { f2bf(fb[4]), f2bf(fb[5]), f2bf(fb[6]), f2bf(fb[7]) };
        *(short4*)&Bs[bn][kk]     = lo;
        *(short4*)&Bs[bn][kk + 4] = hi;
    }
    __syncthreads();

    f32x4 acc[4];
    const f32x4 z = {0.f, 0.f, 0.f, 0.f};
    #pragma unroll
    for (int j = 0; j < 4; ++j) acc[j] = z;

    #pragma unroll
    for (int k0 = 0; k0 < C; k0 += 32) {
        bf16x8 a = *(const bf16x8*)&attnb[(size_t)(m0 + 16 * wv + m) * C + k0 + 8 * quad];
        bf16x8 b[4];
        #pragma unroll
        for (int j = 0; j < 4; ++j) b[j] = *(const bf16x8*)&Bs[16 * j + m][k0 + 8 * quad];
        #pragma unroll
        for (int j = 0; j < 4; ++j)
            acc[j] = __builtin_amdgcn_mfma_f32_16x16x32_bf16(a, b[j], acc[j], 0, 0, 0);
    }

    // epilogue: out[nb][c][t] = acc + b[c] + image, float4 along t
    const int tb = t0 + 16 * wv + 4 * quad;
    #pragma unroll
    for (int j = 0; j < 4; ++j) {
        int c = n0 + 16 * j + m;
        float bias = bmix[c];
        size_t o = (size_t)(nb * C + c) * T + tb;
        float4 img = *(const float4*)&image[o];
        float4 res = { acc[j][0] + bias + img.x,
                       acc[j][1] + bias + img.y,
                       acc[j][2] + bias + img.z,
                       acc[j][3] + bias + img.w };
        *(float4*)&out[o] = res;
    }
}

// ---------------------------------------------------------------------------
extern "C" void kernel_launch(void* const* d_in, const int* in_sizes, int n_in,
                              void* d_out, int out_size, void* d_ws, size_t ws_size,
                              hipStream_t stream) {
    const float* image = (const float*)d_in[0];
    const float* w_kqv = (const float*)d_in[1];
    const float* b_kqv = (const float*)d_in[2];
    const float* w_mix = (const float*)d_in[3];
    const float* b_mix = (const float*)d_in[4];
    float* out = (float*)d_out;

    short* Kb    = (short*)d_ws;                       // [nb*h][1024][32]
    short* Qb    = Kb  + (size_t)NB * NH * T * HD;     // [nb*h][1024][32]
    short* Vtb   = Qb  + (size_t)NB * NH * T * HD;     // [nb*h][16][32][64]
    short* attnb = Vtb + (size_t)NB * NH * T * HD;     // [8192][256]

    kqv_mfma<<<dim3(C3 / 64, NB * T / 128), 256, 0, stream>>>(image, w_kqv, b_kqv, Kb, Qb, Vtb);
    attn_mfma<<<dim3(8, NH, NB), 256, 0, stream>>>(Kb, Qb, Vtb, attnb);
    mix_mfma<<<dim3(C / 64, NB * T / 64), 256, 0, stream>>>(attnb, w_mix, b_mix, image, out);
}

// Round 11
// 109.888 us; speedup vs baseline: 1.0255x; 1.0255x over previous
//
#include <hip/hip_runtime.h>
#include <math.h>

// Problem constants
constexpr int NB  = 8;     // batch
constexpr int C   = 256;   // channels
constexpr int T   = 1024;  // pixels (32*32)
constexpr int NH  = 8;     // heads
constexpr int HD  = 32;    // head dim
constexpr int C3  = 768;   // 3*C

// Q pre-scale: (1/sqrt(32)) * log2(e)  -> softmax body is a bare v_exp_f32
constexpr float QSCALE = 0.25503489422229562f;

typedef __attribute__((ext_vector_type(8))) short bf16x8;
typedef __attribute__((ext_vector_type(4))) float f32x4;

__device__ inline short f2bf(float f) {            // round-to-nearest-even
    unsigned u = __float_as_uint(f);
    u += 0x7FFF + ((u >> 16) & 1);
    return (short)(u >> 16);
}
__device__ inline short f2bf_trunc(float f) {      // 1-op truncation (P only)
    return (short)(__float_as_uint(f) >> 16);
}

// ---------------------------------------------------------------------------
// R11 = exact revert to R8 (measured best: 108.5 us).
// R10's 64-row deterministic pairing regressed (+4.2 us): halving per-iter
// MFMA work kept the latency chain length while doubling prologue count.
// ---------------------------------------------------------------------------

// ---------------------------------------------------------------------------
// Kernel 1: KQV projection, bf16 MFMA, 128x64 (m x n) tile, BK=32.
// Inputs read fp32, transpose-converted in the LDS staging scatter.
// K/Q written head-major [nb][h][t][d]; V written TRANSPOSED per 64-row tile:
// Vtb[nb][h][tile=t/64][d][t%64] so attention can read PV B-frags directly
// from global as contiguous 16B. Q pre-scaled by QSCALE.
// ---------------------------------------------------------------------------
__global__ __launch_bounds__(256) void kqv_mfma(const float* __restrict__ image,
                                                const float* __restrict__ wkqv,
                                                const float* __restrict__ bkqv,
                                                short* __restrict__ Kb,
                                                short* __restrict__ Qb,
                                                short* __restrict__ Vtb) {
    __shared__ __align__(16) short As[128][40];
    __shared__ __align__(16) short Bs[64][40];
    const int tid = threadIdx.x;
    const int n0 = blockIdx.x * 64;        // 0..704
    const int m0 = blockIdx.y * 128;
    const int nb = m0 >> 10, t0 = m0 & 1023;
    const int wv = tid >> 6, lane = tid & 63;
    const int m = lane & 15, quad = lane >> 4;
    const int am = tid & 63, ak8 = (tid >> 6) * 8;    // staging map (both A & B)

    const float* imgn = image + (size_t)nb * C * T;

    f32x4 acc[2][4];
    const f32x4 z = {0.f, 0.f, 0.f, 0.f};
    #pragma unroll
    for (int i = 0; i < 2; ++i)
        #pragma unroll
        for (int j = 0; j < 4; ++j) acc[i][j] = z;

    // prefetch first K-slab (fp32): A two 64-row halves, B one 64-col tile
    float fa[2][8], fb[8];
    #pragma unroll
    for (int i = 0; i < 8; ++i) {
        fa[0][i] = imgn[(size_t)(ak8 + i) * T + t0 + am];
        fa[1][i] = imgn[(size_t)(ak8 + i) * T + t0 + 64 + am];
        fb[i]    = wkqv[(size_t)(ak8 + i) * C3 + n0 + am];
    }

    for (int k0 = 0; k0 < C; k0 += 32) {
        __syncthreads();                   // prior frag reads done
        #pragma unroll
        for (int h2 = 0; h2 < 2; ++h2) {
            short4 lo = { f2bf(fa[h2][0]), f2bf(fa[h2][1]), f2bf(fa[h2][2]), f2bf(fa[h2][3]) };
            short4 hi = { f2bf(fa[h2][4]), f2bf(fa[h2][5]), f2bf(fa[h2][6]), f2bf(fa[h2][7]) };
            *(short4*)&As[64 * h2 + am][ak8]     = lo;
            *(short4*)&As[64 * h2 + am][ak8 + 4] = hi;
        }
        {
            short4 lo = { f2bf(fb[0]), f2bf(fb[1]), f2bf(fb[2]), f2bf(fb[3]) };
            short4 hi = { f2bf(fb[4]), f2bf(fb[5]), f2bf(fb[6]), f2bf(fb[7]) };
            *(short4*)&Bs[am][ak8]     = lo;
            *(short4*)&Bs[am][ak8 + 4] = hi;
        }
        if (k0 + 32 < C) {
            #pragma unroll
            for (int i = 0; i < 8; ++i) {
                fa[0][i] = imgn[(size_t)(k0 + 32 + ak8 + i) * T + t0 + am];
                fa[1][i] = imgn[(size_t)(k0 + 32 + ak8 + i) * T + t0 + 64 + am];
                fb[i]    = wkqv[(size_t)(k0 + 32 + ak8 + i) * C3 + n0 + am];
            }
        }
        __syncthreads();
        bf16x8 a[2], b[4];
        #pragma unroll
        for (int i = 0; i < 2; ++i) a[i] = *(const bf16x8*)&As[32 * wv + 16 * i + m][8 * quad];
        #pragma unroll
        for (int j = 0; j < 4; ++j) b[j] = *(const bf16x8*)&Bs[16 * j + m][8 * quad];
        #pragma unroll
        for (int i = 0; i < 2; ++i)
            #pragma unroll
            for (int j = 0; j < 4; ++j)
                acc[i][j] = __builtin_amdgcn_mfma_f32_16x16x32_bf16(a[i], b[j], acc[i][j], 0, 0, 0);
    }

    // epilogue: col jj -> (chunk,h,d); rows = 4 consecutive t per reg set
    #pragma unroll
    for (int j = 0; j < 4; ++j) {
        int jj = n0 + 16 * j + m;
        int chunk = jj >> 8, hh = (jj >> 5) & 7, d = jj & 31;
        float bias = bkqv[jj];
        if (chunk < 2) {
            short* dst = (chunk == 0) ? Kb : Qb;
            float mul = (chunk == 1) ? QSCALE : 1.0f;
            size_t base = (size_t)(nb * NH + hh) * T * HD + d;
            #pragma unroll
            for (int i = 0; i < 2; ++i) {
                int t = t0 + 32 * wv + 16 * i + 4 * quad;
                #pragma unroll
                for (int r = 0; r < 4; ++r)
                    dst[base + (size_t)(t + r) * HD] = f2bf((acc[i][j][r] + bias) * mul);
            }
        } else {
            // V: transposed tile layout [nb][h][tile][d][64]
            size_t base = (size_t)(nb * NH + hh) * (16 * 2048) + (size_t)d * 64;
            #pragma unroll
            for (int i = 0; i < 2; ++i) {
                #pragma unroll
                for (int r = 0; r < 4; ++r) {
                    int t = t0 + 32 * wv + 16 * i + 4 * quad + r;
                    Vtb[base + (size_t)(t >> 6) * 2048 + (t & 63)] = f2bf(acc[i][j][r] + bias);
                }
            }
        }
    }
}

// ---------------------------------------------------------------------------
// Kernel 2: causal flash attention — BARRIER-FREE (R8 structure).
// All MFMA fragments except P load directly from global as contiguous 16B:
//   Q A-frag : Qb[row m][8quad..]        (loaded once per q-tile, regs)
//   K B-frag : Kb[16j+m][8quad..]        (4 loads/iter, L1-hot, prefetched)
//   V B-frag : Vtb[tile][m][32kc+8quad..] (pre-transposed by kqv, prefetched)
// Ps (P bf16, C-layout -> A-layout round trip) is the ONLY LDS, and each
// wave touches only its own 32-row band -> no __syncthreads anywhere.
// grid (8, NH, NB) = 512 blocks, 2/CU; qb = (nb&4)? 7-x : x pairs co-resident
// blocks {qb, 7-qb} so every CU gets ~18 iterations total.
// ---------------------------------------------------------------------------
__global__ __launch_bounds__(256) void attn_mfma(const short* __restrict__ Kb,
                                                 const short* __restrict__ Qb,
                                                 const short* __restrict__ Vtb,
                                                 short* __restrict__ attnb) {
    const int qb = (blockIdx.z & 4) ? 7 - blockIdx.x : blockIdx.x;   // 0..7
    const int h  = blockIdx.y;
    const int nb = blockIdx.z;
    const int tid  = threadIdx.x;
    const int wv   = tid >> 6;
    const int lane = tid & 63;
    const int m    = lane & 15;
    const int quad = lane >> 4;

    __shared__ __align__(16) short Ps[128][72];     // probs bf16, wave-private bands

    const int q0  = qb * 128;
    const int nst = 2 * qb + 2;
    const size_t hb = (size_t)(nb * NH + h) * T * HD;
    const short* Kp = Kb + hb;
    const short* Qp = Qb + hb;
    const short* Vp = Vtb + (size_t)(nb * NH + h) * (16 * 2048);
    const f32x4 z = {0.f, 0.f, 0.f, 0.f};

    // Q fragments: held in registers for the whole loop
    bf16x8 aq[2];
    #pragma unroll
    for (int i = 0; i < 2; ++i)
        aq[i] = *(const bf16x8*)&Qp[(size_t)(q0 + 32 * wv + 16 * i + m) * HD + 8 * quad];

    // preload K/V fragments for st = 0
    bf16x8 bk[4], vb[2][2];
    #pragma unroll
    for (int j = 0; j < 4; ++j)
        bk[j] = *(const bf16x8*)&Kp[(size_t)(16 * j + m) * HD + 8 * quad];
    #pragma unroll
    for (int kc = 0; kc < 2; ++kc)
        #pragma unroll
        for (int hf = 0; hf < 2; ++hf)
            vb[kc][hf] = *(const bf16x8*)&Vp[(size_t)(16 * hf + m) * 64 + 32 * kc + 8 * quad];

    f32x4 O[2][2] = {{z, z}, {z, z}};
    float lp[2][4] = {};

    for (int st = 0; st < nst; ++st) {
        // S = Q K^T : 2 row-groups x 4 col-tiles = 8 MFMA
        f32x4 S[2][4];
        #pragma unroll
        for (int i = 0; i < 2; ++i)
            #pragma unroll
            for (int j = 0; j < 4; ++j)
                S[i][j] = __builtin_amdgcn_mfma_f32_16x16x32_bf16(aq[i], bk[j], z, 0, 0, 0);

        // prefetch next K tile (consumed next iteration)
        if (st + 1 < nst) {
            #pragma unroll
            for (int j = 0; j < 4; ++j)
                bk[j] = *(const bf16x8*)&Kp[(size_t)((st + 1) * 64 + 16 * j + m) * HD + 8 * quad];
        }

        // softmax: bare exp2 (Q pre-scaled); mask only the last two iters
        const bool msk = (st >= 2 * qb);
        const int s0 = st * 64;
        #pragma unroll
        for (int i = 0; i < 2; ++i) {
            const int qr_base = q0 + 32 * wv + 16 * i + 4 * quad;
            #pragma unroll
            for (int j = 0; j < 4; ++j) {
                const int sc = s0 + 16 * j + m;
                #pragma unroll
                for (int r = 0; r < 4; ++r) {
                    float e = __builtin_amdgcn_exp2f(S[i][j][r]);
                    if (msk && sc > qr_base + r) e = 0.f;
                    lp[i][r] += e;
                    Ps[32 * wv + 16 * i + 4 * quad + r][16 * j + m] = f2bf_trunc(e);
                }
            }
        }

        // O += P V (Ps band is wave-private; lgkmcnt ordering suffices)
        #pragma unroll
        for (int kc = 0; kc < 2; ++kc) {
            bf16x8 ap0 = *(const bf16x8*)&Ps[32 * wv + m][32 * kc + 8 * quad];
            bf16x8 ap1 = *(const bf16x8*)&Ps[32 * wv + 16 + m][32 * kc + 8 * quad];
            O[0][0] = __builtin_amdgcn_mfma_f32_16x16x32_bf16(ap0, vb[kc][0], O[0][0], 0, 0, 0);
            O[0][1] = __builtin_amdgcn_mfma_f32_16x16x32_bf16(ap0, vb[kc][1], O[0][1], 0, 0, 0);
            O[1][0] = __builtin_amdgcn_mfma_f32_16x16x32_bf16(ap1, vb[kc][0], O[1][0], 0, 0, 0);
            O[1][1] = __builtin_amdgcn_mfma_f32_16x16x32_bf16(ap1, vb[kc][1], O[1][1], 0, 0, 0);
        }

        // prefetch next V tile (consumed at next iteration's PV)
        if (st + 1 < nst) {
            const short* Vn = Vp + (size_t)(st + 1) * 2048;
            #pragma unroll
            for (int kc = 0; kc < 2; ++kc)
                #pragma unroll
                for (int hf = 0; hf < 2; ++hf)
                    vb[kc][hf] = *(const bf16x8*)&Vn[(size_t)(16 * hf + m) * 64 + 32 * kc + 8 * quad];
        }
    }

    // epilogue: reduce l across 16 m-lanes once, normalize, store bf16
    #pragma unroll
    for (int i = 0; i < 2; ++i)
        #pragma unroll
        for (int r = 0; r < 4; ++r) {
            float l = lp[i][r];
            l += __shfl_xor(l, 1);
            l += __shfl_xor(l, 2);
            l += __shfl_xor(l, 4);
            l += __shfl_xor(l, 8);
            float inv = 1.f / l;
            int row = q0 + 32 * wv + 16 * i + 4 * quad + r;
            short* op = attnb + ((size_t)(nb * T + row)) * C + h * HD;
            op[m]      = f2bf(O[i][0][r] * inv);
            op[16 + m] = f2bf(O[i][1][r] * inv);
        }
}

// ---------------------------------------------------------------------------
// Kernel 3: mix projection + residual. A-frags (attnb, k-contiguous) load
// DIRECTLY from global; w_mix tile (256x64) is transpose-staged into LDS once
// -> ONE barrier total, fully-unrolled barrier-free K-loop.
// ---------------------------------------------------------------------------
__global__ __launch_bounds__(256) void mix_mfma(const short* __restrict__ attnb,
                                                const float* __restrict__ wmix,
                                                const float* __restrict__ bmix,
                                                const float* __restrict__ image,
                                                float* __restrict__ out) {
    __shared__ __align__(16) short Bs[64][264];   // [n][k], stride 264 (16B-mult)
    const int tid = threadIdx.x;
    const int n0 = blockIdx.x * 64;        // 0..192
    const int m0 = blockIdx.y * 64;
    const int nb = m0 >> 10, t0 = m0 & 1023;
    const int wv = tid >> 6, lane = tid & 63;
    const int m = lane & 15, quad = lane >> 4;
    const int bn = tid & 63, bk8 = (tid >> 6) * 8;   // staging: n, k-base

    // stage entire B tile (transpose-convert): k = bk8 + 32g + i
    #pragma unroll
    for (int g = 0; g < 8; ++g) {
        int kk = bk8 + 32 * g;
        float fb[8];
        #pragma unroll
        for (int i = 0; i < 8; ++i)
            fb[i] = wmix[(size_t)(kk + i) * C + n0 + bn];
        short4 lo = { f2bf(fb[0]), f2bf(fb[1]), f2bf(fb[2]), f2bf(fb[3]) };
        short4 hi = { f2bf(fb[4]), f2bf(fb[5]), f2bf(fb[6]), f2bf(fb[7]) };
        *(short4*)&Bs[bn][kk]     = lo;
        *(short4*)&Bs[bn][kk + 4] = hi;
    }
    __syncthreads();

    f32x4 acc[4];
    const f32x4 z = {0.f, 0.f, 0.f, 0.f};
    #pragma unroll
    for (int j = 0; j < 4; ++j) acc[j] = z;

    #pragma unroll
    for (int k0 = 0; k0 < C; k0 += 32) {
        bf16x8 a = *(const bf16x8*)&attnb[(size_t)(m0 + 16 * wv + m) * C + k0 + 8 * quad];
        bf16x8 b[4];
        #pragma unroll
        for (int j = 0; j < 4; ++j) b[j] = *(const bf16x8*)&Bs[16 * j + m][k0 + 8 * quad];
        #pragma unroll
        for (int j = 0; j < 4; ++j)
            acc[j] = __builtin_amdgcn_mfma_f32_16x16x32_bf16(a, b[j], acc[j], 0, 0, 0);
    }

    // epilogue: out[nb][c][t] = acc + b[c] + image, float4 along t
    const int tb = t0 + 16 * wv + 4 * quad;
    #pragma unroll
    for (int j = 0; j < 4; ++j) {
        int c = n0 + 16 * j + m;
        float bias = bmix[c];
        size_t o = (size_t)(nb * C + c) * T + tb;
        float4 img = *(const float4*)&image[o];
        float4 res = { acc[j][0] + bias + img.x,
                       acc[j][1] + bias + img.y,
                       acc[j][2] + bias + img.z,
                       acc[j][3] + bias + img.w };
        *(float4*)&out[o] = res;
    }
}

// ---------------------------------------------------------------------------
extern "C" void kernel_launch(void* const* d_in, const int* in_sizes, int n_in,
                              void* d_out, int out_size, void* d_ws, size_t ws_size,
                              hipStream_t stream) {
    const float* image = (const float*)d_in[0];
    const float* w_kqv = (const float*)d_in[1];
    const float* b_kqv = (const float*)d_in[2];
    const float* w_mix = (const float*)d_in[3];
    const float* b_mix = (const float*)d_in[4];
    float* out = (float*)d_out;

    short* Kb    = (short*)d_ws;                       // [nb*h][1024][32]
    short* Qb    = Kb  + (size_t)NB * NH * T * HD;     // [nb*h][1024][32]
    short* Vtb   = Qb  + (size_t)NB * NH * T * HD;     // [nb*h][16][32][64]
    short* attnb = Vtb + (size_t)NB * NH * T * HD;     // [8192][256]

    kqv_mfma<<<dim3(C3 / 64, NB * T / 128), 256, 0, stream>>>(image, w_kqv, b_kqv, Kb, Qb, Vtb);
    attn_mfma<<<dim3(8, NH, NB), 256, 0, stream>>>(Kb, Qb, Vtb, attnb);
    mix_mfma<<<dim3(C / 64, NB * T / 64), 256, 0, stream>>>(attnb, w_mix, b_mix, image, out);
}